// Round 12
// baseline (2523.686 us; speedup 1.0000x reference)
//
#include <hip/hip_runtime.h>
#include <stdint.h>

typedef unsigned int u32;
typedef _Float16 f16;
typedef __attribute__((ext_vector_type(16))) float    f32x16;
typedef __attribute__((ext_vector_type(4)))  float    f32x4;
typedef __attribute__((ext_vector_type(8)))  _Float16 f16x8;
typedef __attribute__((ext_vector_type(4)))  _Float16 f16x4;

#define DIM    1024
#define NROWS  8192
#define NLAYER 10

// ---------- weight packer: f32 W -> MFMA-fragment-ordered f16 chunks ----------
// Chunk (l, c32, kc): 1 KB. Lane holds A-operand frag of v_mfma_f32_32x32x16_f16:
//   W[c32*32 + (lane&31)][kc*16 + (lane>>5)*8 + j], j=0..7  (16 B per lane)
__global__ __launch_bounds__(256) void pack_weights(const float* __restrict__ W0,
                                                    const float* __restrict__ Wh,
                                                    f16* __restrict__ Wp) {
    int g    = blockIdx.x * 4 + (threadIdx.x >> 6);   // wave id = chunk id, 20480 total
    int lane = threadIdx.x & 63;
    int l    = g >> 11;
    int c32  = (g >> 6) & 31;
    int kc   = g & 63;
    int n  = c32 * 32 + (lane & 31);
    int k  = kc * 16 + (lane >> 5) * 8;
    const float* src = (l == 0 ? W0 : Wh + (size_t)(l - 1) * DIM * DIM) + (size_t)n * DIM + k;
    float4 w0 = *(const float4*)src;
    float4 w1 = *(const float4*)(src + 4);
    f16x8 o;
    o[0] = (f16)w0.x; o[1] = (f16)w0.y; o[2] = (f16)w0.z; o[3] = (f16)w0.w;
    o[4] = (f16)w1.x; o[5] = (f16)w1.y; o[6] = (f16)w1.z; o[7] = (f16)w1.w;
    *(f16x8*)((char*)Wp + (size_t)g * 1024 + lane * 16) = o;
}

// ---------- paired-block row-local chain ----------
// 256 blocks x 1024 threads (16 waves). Pair p = bid-derived; the two halves
// compute cols [half*512,+512) of the SAME 64 rows. h[64][1024] f16 lives in
// LDS fragment-linear (frag(kc,rg) at (kc*2+rg)*1024 + lane*16; k-loop reads
// are lane-linear => conflict-free). Wave w: W-chunk c32 = half*16+w streamed
// global->reg depth-8; h frags depth-2; 2 MFMA/kc (reuse 2 via row-groups).
// Per layer: in-place epilogue (own cols), pairwise h-half exchange through a
// global ping-pong buffer with r6-proven release/flag/acquire (per-pair only).
__global__ __launch_bounds__(1024, 2) void mono_chain(
        const float* __restrict__ x,
        const f16* __restrict__ Wp,
        const float* __restrict__ b0g,
        const float* __restrict__ bh,
        const float* __restrict__ Wout,
        const float* __restrict__ bout,
        f16* __restrict__ xbuf,
        u32* __restrict__ flags,
        float* __restrict__ out) {
    __shared__ char lds[135168];   // h 128 KB + 4 KB gemv reduce buffer

    const int tid  = threadIdx.x;
    const int lane = tid & 63;
    const int wid  = tid >> 6;        // 0..15

    // pair placement: XCD(bid) = bid%8 (round-robin dispatch). Map so both
    // halves of a pair land on the SAME XCD: bid = (p%8) + 8*(2*(p/8) + half)
    const int bid  = blockIdx.x;
    const int xcd  = bid & 7;
    const int y    = bid >> 3;        // 0..31
    const int half = y & 1;
    const int pair = (y >> 1) * 8 + xcd;   // 0..127
    const int r0   = pair * 64;

    // ---- stage x rows r0..r0+63 -> h (f32 -> f16, fragment-linear) ----
    {
        const int rg = lane >> 5, rr = lane & 31;
        const float* src = x + (size_t)(r0 + lane) * DIM + wid * 64;
        #pragma unroll
        for (int i = 0; i < 16; ++i) {
            float4 v = *(const float4*)(src + i * 4);
            f16x4 o;
            o.x = (f16)v.x; o.y = (f16)v.y; o.z = (f16)v.z; o.w = (f16)v.w;
            int kc    = wid * 4 + (i >> 2);
            int khalf = (i >> 1) & 1;
            *(f16x4*)(lds + ((kc * 2 + rg) << 10) + (rr + (khalf << 5)) * 16 + (i & 1) * 8) = o;
        }
    }
    __syncthreads();

    const char* hL  = lds + lane * 16;
    const int   c32 = half * 16 + wid;          // this wave's 32-col chunk

    for (int l = 0; l < NLAYER; ++l) {
        const char* wbase = (const char*)Wp + (size_t)l * 2097152
                          + (size_t)c32 * 65536 + lane * 16;

        f32x16 acc0 = (f32x16)(0.f), acc1 = (f32x16)(0.f);

        // prologue: W depth-8, h depth-2 (named slots, rule #20)
        f16x8 q0, q1, q2, q3, q4, q5, q6, q7, p0A, p0B, p1A, p1B;
        q0 = *(const f16x8*)(wbase);
        q1 = *(const f16x8*)(wbase + 1024);
        q2 = *(const f16x8*)(wbase + 2048);
        q3 = *(const f16x8*)(wbase + 3072);
        q4 = *(const f16x8*)(wbase + 4096);
        q5 = *(const f16x8*)(wbase + 5120);
        q6 = *(const f16x8*)(wbase + 6144);
        q7 = *(const f16x8*)(wbase + 7168);
        p0A = *(const f16x8*)(hL);          p0B = *(const f16x8*)(hL + 1024);
        p1A = *(const f16x8*)(hL + 2048);   p1B = *(const f16x8*)(hL + 3072);

#define STEP(Q, PA, PB, KW, KH)                                                \
        __builtin_amdgcn_s_setprio(1);                                         \
        acc0 = __builtin_amdgcn_mfma_f32_32x32x16_f16(Q, PA, acc0, 0, 0, 0);   \
        acc1 = __builtin_amdgcn_mfma_f32_32x32x16_f16(Q, PB, acc1, 0, 0, 0);   \
        __builtin_amdgcn_s_setprio(0);                                         \
        Q  = *(const f16x8*)(wbase + (size_t)((KW) & 63) * 1024);              \
        PA = *(const f16x8*)(hL + (size_t)((KH) & 63) * 2048);                 \
        PB = *(const f16x8*)(hL + (size_t)((KH) & 63) * 2048 + 1024);

        for (int t = 0; t < 8; ++t) {
            int b = t * 8;
            STEP(q0, p0A, p0B, b + 8,  b + 2)
            STEP(q1, p1A, p1B, b + 9,  b + 3)
            STEP(q2, p0A, p0B, b + 10, b + 4)
            STEP(q3, p1A, p1B, b + 11, b + 5)
            STEP(q4, p0A, p0B, b + 12, b + 6)
            STEP(q5, p1A, p1B, b + 13, b + 7)
            STEP(q6, p0A, p0B, b + 14, b + 8)
            STEP(q7, p1A, p1B, b + 15, b + 9)
        }
#undef STEP

        __syncthreads();   // all h reads done -> in-place overwrite safe

        // ---- epilogue: bias + sigmoid -> f16 into own-col LDS region ----
        // D: row = (lane&31)+32*rgp; col = c32*32 + g2*8 + 4*(lane>>5) + j
        const float* bias = l ? (bh + (size_t)(l - 1) * DIM) : b0g;
        const int rD   = lane & 31;
        const int hsel = lane >> 5;
#define EPI(ACC, RGP)                                                          \
        {                                                                      \
            _Pragma("unroll")                                                  \
            for (int g2 = 0; g2 < 4; ++g2) {                                   \
                int c = c32 * 32 + g2 * 8 + 4 * hsel;                          \
                f32x4 bv = *(const f32x4*)(bias + c);                          \
                f16x4 o;                                                       \
                _Pragma("unroll")                                              \
                for (int j = 0; j < 4; ++j) {                                  \
                    float z = ACC[g2 * 4 + j] + bv[j];                         \
                    o[j] = (f16)(1.0f / (1.0f + __expf(-z)));                  \
                }                                                              \
                int kc2 = c32 * 2 + (g2 >> 1);                                 \
                *(f16x4*)(lds + ((kc2 * 2 + (RGP)) << 10)                      \
                              + (rD + ((g2 & 1) << 5)) * 16 + hsel * 8) = o;   \
            }                                                                  \
        }
        EPI(acc0, 0)
        EPI(acc1, 1)
#undef EPI
        __syncthreads();   // own-half h_next visible in LDS

        // ---- pairwise exchange: own 64KB half -> xbuf; partner half <- xbuf ----
        const int slot = l & 1;
        char* xme = (char*)xbuf + (size_t)(((pair * 2 + slot) * 2) + half) * 65536;
        const char* xpt = (const char*)xbuf + (size_t)(((pair * 2 + slot) * 2) + (half ^ 1)) * 65536;
        {   // coalesced 64KB copy LDS(own region) -> global
            const char* src = lds + half * 65536;
            #pragma unroll
            for (int i = 0; i < 4; ++i)
                *(f32x4*)(xme + i * 16384 + tid * 16) =
                    *(const f32x4*)(src + i * 16384 + tid * 16);
        }
        __syncthreads();                    // all waves' stores vmcnt-drained
        if (tid == 0) {
            __threadfence();                // release: L2 -> coherence point
            atomicAdd(&flags[(pair * 10 + l) * 16], 1u);
            while (__hip_atomic_load(&flags[(pair * 10 + l) * 16],
                                     __ATOMIC_RELAXED, __HIP_MEMORY_SCOPE_AGENT) < 2u)
                __builtin_amdgcn_s_sleep(1);
            __threadfence();                // acquire: invalidate stale lines
        }
        __syncthreads();
        {   // coalesced 64KB copy global(partner) -> LDS(partner region)
            char* dst = lds + (half ^ 1) * 65536;
            #pragma unroll
            for (int i = 0; i < 4; ++i)
                *(f32x4*)(dst + i * 16384 + tid * 16) =
                    *(const f32x4*)(xpt + i * 16384 + tid * 16);
        }
        __syncthreads();   // full h_next resident before next layer
    }

    // ---- output gemv: wave w sums k in [w*64,+64) for all 64 rows ----
    {
        const int rg = lane >> 5, rr = lane & 31;   // thread row = lane
        float s = 0.f;
        #pragma unroll
        for (int i = 0; i < 8; ++i) {
            int k  = wid * 64 + i * 8;
            int kc = k >> 4;
            f16x8 h8 = *(const f16x8*)(lds + ((kc * 2 + rg) << 10)
                                           + (rr + ((i & 1) << 5)) * 16);
            const float* w = Wout + k;
            f32x4 w0 = *(const f32x4*)w;
            f32x4 w1 = *(const f32x4*)(w + 4);
            s += (float)h8[0] * w0[0] + (float)h8[1] * w0[1]
               + (float)h8[2] * w0[2] + (float)h8[3] * w0[3]
               + (float)h8[4] * w1[0] + (float)h8[5] * w1[1]
               + (float)h8[6] * w1[2] + (float)h8[7] * w1[3];
        }
        float* sb = (float*)(lds + 131072);
        sb[wid * 64 + lane] = s;
        __syncthreads();
        if (tid < 64) {
            float tot = 0.f;
            #pragma unroll
            for (int w = 0; w < 16; ++w) tot += sb[w * 64 + tid];
            out[r0 + tid] = tot + bout[0];   // both halves write identical value
        }
    }
}

// ---------- launcher ----------
extern "C" void kernel_launch(void* const* d_in, const int* in_sizes, int n_in,
                              void* d_out, int out_size, void* d_ws, size_t ws_size,
                              hipStream_t stream) {
    const float* x    = (const float*)d_in[0];
    const float* W0   = (const float*)d_in[1];
    const float* b0   = (const float*)d_in[2];
    const float* Wh   = (const float*)d_in[3];
    const float* bh   = (const float*)d_in[4];
    const float* Wout = (const float*)d_in[5];
    const float* bout = (const float*)d_in[6];
    float* out = (float*)d_out;

    f16* Wp   = (f16*)d_ws;                                   // 20 MB
    f16* xbuf = Wp + (size_t)NLAYER * DIM * DIM;              // 32 MB exchange
    u32* flags = (u32*)(xbuf + (size_t)128 * 2 * 2 * 32768);  // 80 KB

    hipMemsetAsync(flags, 0, 128 * NLAYER * 16 * sizeof(u32), stream);
    pack_weights<<<NLAYER * 32 * 64 / 4, 256, 0, stream>>>(W0, Wh, Wp);
    mono_chain<<<256, 1024, 0, stream>>>(x, Wp, b0, bh, Wout, bout, xbuf, flags, out);
}